// Round 3
// baseline (1874.768 us; speedup 1.0000x reference)
//
#include <hip/hip_runtime.h>

#define TT   512
#define IDIM 64
#define HDIM 256

typedef short  short8  __attribute__((ext_vector_type(8)));
typedef short  short4v __attribute__((ext_vector_type(4)));
typedef float  f32x4   __attribute__((ext_vector_type(4)));
typedef unsigned int       u32;
typedef unsigned long long u64;

__device__ __forceinline__ short f2bf(float f) {
    unsigned u = __float_as_uint(f);
    u = u + 0x7FFFu + ((u >> 16) & 1u);   // round-to-nearest-even
    return (short)(u >> 16);
}
__device__ __forceinline__ u32 f2bf_u(float f) {
    unsigned u = __float_as_uint(f);
    u = u + 0x7FFFu + ((u >> 16) & 1u);
    return (u >> 16);                      // bf16 in low 16 bits
}
__device__ __forceinline__ float bf2f(short h) {
    return __uint_as_float(((unsigned)(unsigned short)h) << 16);
}
__device__ __forceinline__ float sigm(float x)  { return 1.0f / (1.0f + __expf(-x)); }
__device__ __forceinline__ float tanh_(float x) { return 2.0f / (1.0f + __expf(-2.0f * x)) - 1.0f; }

// 256 persistent workgroups = 16 batch-groups x 16 hidden-chunks.
// h exchange: SELF-VALIDATING tagged words. h word = (bf16<<16) | (step_tag).
// Every elementwise thread stores its own word (relaxed agent atomic, sc1 ->
// write-through, clique's shared XCD-L2 serves readers). Readers poll the data
// words directly until all tags match -- no flags, no fences, no vmcnt ordering.
// Parity double-buffer; writer-ahead skew bounded at 1 step by the data dep.
__global__ __launch_bounds__(256, 1) void lstm_fused(
    const float* __restrict__ x,
    const float* __restrict__ Wih0, const float* __restrict__ Whh0,
    const float* __restrict__ bih0, const float* __restrict__ bhh0,
    const float* __restrict__ Wih1, const float* __restrict__ Whh1,
    const float* __restrict__ bih1, const float* __restrict__ bhh1,
    const float* __restrict__ Wfc,  const float* __restrict__ bfc,
    float* __restrict__ out, char* __restrict__ ws)
{
    u32* h0w = (u32*)ws;                  // [2][16][16][256] tagged words (1 MB)
    u32* h1w = h0w + 2 * 16 * 16 * 256;   // [2][16][16][256] tagged words (1 MB)

    const int blk   = blockIdx.x;
    const int grp   = ((blk & 7) << 1) | ((blk >> 3) & 1); // batch-group 0..15
    const int chunk = blk >> 4;                            // hidden-chunk 0..15
    const int tid   = threadIdx.x;
    const int lane  = tid & 63;
    const int wave  = tid >> 6;      // gate index: 0=i 1=f 2=g 3=o
    const int quad  = lane >> 4;
    const int nn    = lane & 15;     // W-row within 16-row tile

    __shared__ short A0[16][328];    // [m][ x(64) | h0(256) ] + pad
    __shared__ short A1[16][520];    // [m][ h0(256) | h1(256) ] + pad
    __shared__ float gbuf[2][4][16][16];
    __shared__ float red[16][16];
    __shared__ float ldspad[13312];  // force 1 wg/CU (total LDS > 80 KiB)

    // zero A buffers (h0[-1] = 0 for the s==0 layer0 step)
    for (int i = tid; i < 16 * 328; i += 256) (&A0[0][0])[i] = 0;
    for (int i = tid; i < 16 * 520; i += 256) (&A1[0][0])[i] = 0;

    // ---- static weight fragments -> registers (B operand: W[n][k], n=lane&15, k=quad*8+j)
    const int wrow = wave * HDIM + chunk * 16 + nn;
    short8 w0f[10];   // layer0: kb 0..1 = Wih0 (K 0..63), kb 2..9 = Whh0 (K 64..319)
    short8 w1f[16];   // layer1: kb 0..7 = Wih1 (K 0..255), kb 8..15 = Whh1 (K 256..511)
#pragma unroll
    for (int kb = 0; kb < 10; ++kb)
#pragma unroll
        for (int j = 0; j < 8; ++j) {
            int k = kb * 32 + quad * 8 + j;
            float v = (k < 64) ? Wih0[wrow * IDIM + k] : Whh0[wrow * HDIM + (k - 64)];
            w0f[kb][j] = f2bf(v);
        }
#pragma unroll
    for (int kb = 0; kb < 16; ++kb)
#pragma unroll
        for (int j = 0; j < 8; ++j) {
            int k = kb * 32 + quad * 8 + j;
            float v = (k < 256) ? Wih1[wrow * HDIM + k] : Whh1[wrow * HDIM + (k - 256)];
            w1f[kb][j] = f2bf(v);
        }
    const float bias0 = bih0[wrow] + bhh0[wrow];
    const float bias1 = bih1[wrow] + bhh1[wrow];

    const int em = tid >> 4;   // elementwise batch row (0..15)
    const int ej = tid & 15;   // elementwise hidden unit group (0..15)
    float c0 = 0.0f, c1 = 0.0f;

    auto load_x = [&](int t) {
        const float4 v = *(const float4*)&x[((size_t)(grp * 16 + em) * TT + t) * IDIM + ej * 4];
        short4v sv;
        sv[0] = f2bf(v.x); sv[1] = f2bf(v.y); sv[2] = f2bf(v.z); sv[3] = f2bf(v.w);
        *(short4v*)&A0[em][ej * 4] = sv;
    };

    __syncthreads();
    load_x(0);
    __syncthreads();

    // super-step s: layer0 computes h0[s] (s<T); layer1 computes h1[s-1] (s>=1)
    for (int s = 0; s <= TT; ++s) {
        const int par = s & 1;
        const u32 tag = (u32)(s + 1);   // 1..513, never 0xAAAA (poison), no wrap

        if (s < TT) {
            f32x4 acc = {0.f, 0.f, 0.f, 0.f};
#pragma unroll
            for (int kb = 0; kb < 10; ++kb) {
                short8 a = *(const short8*)&A0[nn][kb * 32 + quad * 8];
                acc = __builtin_amdgcn_mfma_f32_16x16x32_bf16(a, w0f[kb], acc, 0, 0, 0);
            }
#pragma unroll
            for (int r = 0; r < 4; ++r)
                gbuf[0][wave][quad * 4 + r][nn] = acc[r] + bias0;
        }
        if (s >= 1) {
            f32x4 acc = {0.f, 0.f, 0.f, 0.f};
#pragma unroll
            for (int kb = 0; kb < 16; ++kb) {
                short8 a = *(const short8*)&A1[nn][kb * 32 + quad * 8];
                acc = __builtin_amdgcn_mfma_f32_16x16x32_bf16(a, w1f[kb], acc, 0, 0, 0);
            }
#pragma unroll
            for (int r = 0; r < 4; ++r)
                gbuf[1][wave][quad * 4 + r][nn] = acc[r] + bias1;
        }
        __syncthreads();

        // elementwise cell updates -> publish own tagged words immediately
        const size_t wbase = ((size_t)(par * 16 + grp) * 16 + em) * 256 + chunk * 16 + ej;
        if (s < TT) {
            float gi = sigm (gbuf[0][0][em][ej]);
            float gf = sigm (gbuf[0][1][em][ej]);
            float gg = tanh_(gbuf[0][2][em][ej]);
            float go = sigm (gbuf[0][3][em][ej]);
            c0 = gf * c0 + gi * gg;
            u32 hb = f2bf_u(go * tanh_(c0));
            __hip_atomic_store(&h0w[wbase], (hb << 16) | tag,
                               __ATOMIC_RELAXED, __HIP_MEMORY_SCOPE_AGENT);
        }
        {
            u32 hb = 0;
            if (s >= 1) {
                float gi = sigm (gbuf[1][0][em][ej]);
                float gf = sigm (gbuf[1][1][em][ej]);
                float gg = tanh_(gbuf[1][2][em][ej]);
                float go = sigm (gbuf[1][3][em][ej]);
                c1 = gf * c1 + gi * gg;
                hb = f2bf_u(go * tanh_(c1));
            }
            __hip_atomic_store(&h1w[wbase], (hb << 16) | tag,
                               __ATOMIC_RELAXED, __HIP_MEMORY_SCOPE_AGENT);
        }

        if (s + 1 < TT) load_x(s + 1);   // overlap x prefetch with the poll

        // poll the data words directly: thread (em,ej) gathers units ej*16..+15
        const size_t rbase = ((size_t)(par * 16 + grp) * 16 + em) * 256 + ej * 16;
        u64* p0 = (u64*)&h0w[rbase];
        u64* p1 = (u64*)&h1w[rbase];
        u64 r0[8], r1[8];
        const bool need0 = (s < TT);
        for (;;) {
            u32 bad = 0;
            if (need0) {
#pragma unroll
                for (int i = 0; i < 8; ++i)
                    r0[i] = __hip_atomic_load(&p0[i], __ATOMIC_RELAXED, __HIP_MEMORY_SCOPE_AGENT);
            }
#pragma unroll
            for (int i = 0; i < 8; ++i)
                r1[i] = __hip_atomic_load(&p1[i], __ATOMIC_RELAXED, __HIP_MEMORY_SCOPE_AGENT);
            if (need0) {
#pragma unroll
                for (int i = 0; i < 8; ++i)
                    bad |= (((u32)r0[i] ^ tag) & 0xFFFFu) | ((((u32)(r0[i] >> 32)) ^ tag) & 0xFFFFu);
            }
#pragma unroll
            for (int i = 0; i < 8; ++i)
                bad |= (((u32)r1[i] ^ tag) & 0xFFFFu) | ((((u32)(r1[i] >> 32)) ^ tag) & 0xFFFFu);
            if (!bad) break;
        }

        // strip tags, pack bf16 pairs, write A-tiles for next super-step
        if (need0) {
            u32 w[8];
#pragma unroll
            for (int i = 0; i < 8; ++i) {
                u32 lo = (u32)r0[i], hi = (u32)(r0[i] >> 32);
                w[i] = (lo >> 16) | (hi & 0xFFFF0000u);
            }
            uint4 q0 = {w[0], w[1], w[2], w[3]};
            uint4 q1 = {w[4], w[5], w[6], w[7]};
            *(uint4*)&A0[em][64 + ej * 16]     = q0;
            *(uint4*)&A0[em][64 + ej * 16 + 8] = q1;
            *(uint4*)&A1[em][ej * 16]          = q0;
            *(uint4*)&A1[em][ej * 16 + 8]      = q1;
        }
        {
            u32 w[8];
#pragma unroll
            for (int i = 0; i < 8; ++i) {
                u32 lo = (u32)r1[i], hi = (u32)(r1[i] >> 32);
                w[i] = (lo >> 16) | (hi & 0xFFFF0000u);
            }
            uint4 q0 = {w[0], w[1], w[2], w[3]};
            uint4 q1 = {w[4], w[5], w[6], w[7]};
            *(uint4*)&A1[em][256 + ej * 16]     = q0;
            *(uint4*)&A1[em][256 + ej * 16 + 8] = q1;
        }
        __syncthreads();
    }

    // FC epilogue: A1[:,256..511] holds h1[T-1] (bf16)
    {
        float part = 0.f;
#pragma unroll
        for (int kk = 0; kk < 16; ++kk) {
            int k = ej * 16 + kk;
            part += bf2f(A1[em][256 + k]) * Wfc[k];
        }
        red[em][ej] = part;
    }
    __syncthreads();
    if (chunk == 0 && tid < 16) {
        float sum = bfc[0];
#pragma unroll
        for (int c = 0; c < 16; ++c) sum += red[tid][c];
        out[grp * 16 + tid] = sum;
    }

    // keep ldspad allocated (1 wg/CU); never true at runtime
    if (gridDim.x > 100000) { ldspad[tid] = bias0; out[0] = ldspad[255 - tid]; }
}

extern "C" void kernel_launch(void* const* d_in, const int* in_sizes, int n_in,
                              void* d_out, int out_size, void* d_ws, size_t ws_size,
                              hipStream_t stream) {
    (void)in_sizes; (void)n_in; (void)out_size; (void)ws_size;
    const float* x    = (const float*)d_in[0];
    const float* Wih0 = (const float*)d_in[1];
    const float* Whh0 = (const float*)d_in[2];
    const float* bih0 = (const float*)d_in[3];
    const float* bhh0 = (const float*)d_in[4];
    const float* Wih1 = (const float*)d_in[5];
    const float* Whh1 = (const float*)d_in[6];
    const float* bih1 = (const float*)d_in[7];
    const float* bhh1 = (const float*)d_in[8];
    const float* Wfc  = (const float*)d_in[9];
    const float* bfc  = (const float*)d_in[10];

    lstm_fused<<<256, 256, 0, stream>>>(x, Wih0, Whh0, bih0, bhh0,
                                        Wih1, Whh1, bih1, bhh1, Wfc, bfc,
                                        (float*)d_out, (char*)d_ws);
}